// Round 22
// baseline (242.857 us; speedup 1.0000x reference)
//
#include <hip/hip_runtime.h>
#include <hip/hip_bf16.h>

// ---------------------------------------------------------------------------
// STGCN fused pipeline, round 22.
// conv23 v19 = v18 with GCN-gather-1 FUSED into the stage phase: the block
// gathers its 16 nodes' neighborhoods (bit-identical order to k_gather_bf<20>)
// straight into H2 LDS. Eliminates the hb round-trip (16MB w + 16MB r) and one
// kernel launch. xw2 now written to hb (no read/write aliasing on xwb);
// gather96: hb -> xwb; pool reads xwb.
// ---------------------------------------------------------------------------

#define NN 50000
#define NE 500000
#define NG 16
#define CAP 64

typedef __attribute__((ext_vector_type(8))) short bf16x8;
typedef __attribute__((ext_vector_type(8))) unsigned short u16x8;
typedef __attribute__((ext_vector_type(4))) float f32x4;

__device__ __forceinline__ float sigf(float g) {
    return 1.0f / (1.0f + __expf(-g));
}

__device__ __forceinline__ unsigned short to_bf16(float f) {
    __bf16 b = (__bf16)f;                       // RNE
    return __builtin_bit_cast(unsigned short, b);
}

__device__ __forceinline__ float from_bf16(unsigned short u) {
    return __uint_as_float(((unsigned)u) << 16);
}

// ---- bucket build ---------------------------------------------------------
__global__ void k_fill(const int* __restrict__ row, const int* __restrict__ col,
                       int* __restrict__ cnt, unsigned short* __restrict__ bucket,
                       int E)
{
    int e = blockIdx.x * 256 + threadIdx.x;
    if (e >= E) return;
    int c = col[e];
    int pos = atomicAdd(&cnt[c], 1);
    if (pos < CAP) bucket[(size_t)c * CAP + pos] = (unsigned short)row[e];
}

// ---- weight pack (bf16 RNE) into MFMA A-fragment order --------------------
__global__ void k_prep2(const float* __restrict__ w1b, const float* __restrict__ w2a,
                        const float* __restrict__ ws2,
                        unsigned short* __restrict__ A2h,
                        unsigned short* __restrict__ A3h,
                        unsigned short* __restrict__ APh)
{
    int idx = blockIdx.x * 256 + threadIdx.x;
    if (idx < 1024) {           // conv2: (T,s,lane)
        int lane = idx & 63; int r = idx >> 6; int s = r & 1; int T = r >> 1;
        int m = T * 16 + (lane & 15); int g = lane >> 4;
        for (int i = 0; i < 8; ++i) {
            int k = s * 32 + 8 * g + i;
            float w = 0.f;
            if (k < 48) { int ci = k & 15, kk = k >> 4; w = w1b[m * 48 + ci * 3 + kk]; }
            A2h[idx * 8 + i] = to_bf16(w);
        }
    }
    if (idx < 3072) {           // conv3: (T,s,lane)
        int lane = idx & 63; int r = idx >> 6; int s = r % 6; int T = r / 6;
        int m = T * 16 + (lane & 15); int g = lane >> 4;
        for (int i = 0; i < 8; ++i) {
            int k = s * 32 + 8 * g + i;
            int ci = k & 63, kk = k >> 6;
            A3h[idx * 8 + i] = to_bf16(w2a[m * 192 + ci * 3 + kk]);
        }
    }
    if (idx < 128) {            // proj: (s,lane)
        int lane = idx & 63; int s = idx >> 6;
        int d = lane & 15; int g = lane >> 4;
        for (int i = 0; i < 8; ++i) {
            int co = s * 32 + 8 * g + i;
            APh[idx * 8 + i] = to_bf16(ws2[co * 16 + d]);
        }
    }
}

// ---- conv_glu1 + proj: 2 t-outputs/thread, bf16 output --------------------
__global__ __launch_bounds__(256) void k_conv1_proj2(
    const float* __restrict__ x, const float* __restrict__ w,
    const float* __restrict__ b, const float* __restrict__ W1,
    const int* __restrict__ cnt, unsigned short* __restrict__ xwb, int nNodes)
{
    __shared__ float pk[64 * 28];
    __shared__ float bs[128];
    int tid = threadIdx.x;
    for (int i = tid; i < 1792; i += 256) {
        int c = i / 28, q = i - c * 28;
        float v;
        if (q < 6)       v = w[c * 6 + q];
        else if (q < 12) v = w[(c + 64) * 6 + (q - 6)];
        else             v = W1[c * 16 + (q - 12)];
        pk[i] = v;
    }
    if (tid < 128) bs[tid] = b[tid];
    __syncthreads();

    int idx = blockIdx.x * 256 + tid;
    if (idx >= nNodes * 5) return;
    int n = idx / 5, p = idx - n * 5;
    int t0 = 2 * p;

    float xq[2][4];
#pragma unroll
    for (int ci = 0; ci < 2; ++ci) {
        const float* xp = &x[n * 24 + ci * 12 + t0];
        float2 u0 = *(const float2*)(xp);
        float2 u1 = *(const float2*)(xp + 2);
        xq[ci][0] = u0.x; xq[ci][1] = u0.y; xq[ci][2] = u1.x; xq[ci][3] = u1.y;
    }

    float acc0[16], acc1[16];
#pragma unroll
    for (int d = 0; d < 16; ++d) { acc0[d] = 0.f; acc1[d] = 0.f; }

    for (int c = 0; c < 64; ++c) {
        const float* P = &pk[c * 28];
        float4 A = *(const float4*)(P);
        float4 B = *(const float4*)(P + 4);
        float4 C = *(const float4*)(P + 8);
        float bc = bs[c], bg = bs[c + 64];

        float a0 = bc, g0 = bg;
        a0 = fmaf(A.x, xq[0][0], a0); a0 = fmaf(A.y, xq[0][1], a0); a0 = fmaf(A.z, xq[0][2], a0);
        a0 = fmaf(A.w, xq[1][0], a0); a0 = fmaf(B.x, xq[1][1], a0); a0 = fmaf(B.y, xq[1][2], a0);
        g0 = fmaf(B.z, xq[0][0], g0); g0 = fmaf(B.w, xq[0][1], g0); g0 = fmaf(C.x, xq[0][2], g0);
        g0 = fmaf(C.y, xq[1][0], g0); g0 = fmaf(C.z, xq[1][1], g0); g0 = fmaf(C.w, xq[1][2], g0);
        float h0 = a0 * sigf(g0);

        float a1 = bc, g1 = bg;
        a1 = fmaf(A.x, xq[0][1], a1); a1 = fmaf(A.y, xq[0][2], a1); a1 = fmaf(A.z, xq[0][3], a1);
        a1 = fmaf(A.w, xq[1][1], a1); a1 = fmaf(B.x, xq[1][2], a1); a1 = fmaf(B.y, xq[1][3], a1);
        g1 = fmaf(B.z, xq[0][1], g1); g1 = fmaf(B.w, xq[0][2], g1); g1 = fmaf(C.x, xq[0][3], g1);
        g1 = fmaf(C.y, xq[1][1], g1); g1 = fmaf(C.z, xq[1][2], g1); g1 = fmaf(C.w, xq[1][3], g1);
        float h1 = a1 * sigf(g1);

        float4 D = *(const float4*)(P + 12);
        float4 E = *(const float4*)(P + 16);
        float4 F = *(const float4*)(P + 20);
        float4 G = *(const float4*)(P + 24);
        float wr[16] = {D.x, D.y, D.z, D.w, E.x, E.y, E.z, E.w,
                        F.x, F.y, F.z, F.w, G.x, G.y, G.z, G.w};
#pragma unroll
        for (int d = 0; d < 16; ++d) {
            acc0[d] = fmaf(wr[d], h0, acc0[d]);
            acc1[d] = fmaf(wr[d], h1, acc1[d]);
        }
    }
    float dv = rsqrtf((float)cnt[n] + 1.0f);
    u16x8 p0, p1, p2_, p3_;
#pragma unroll
    for (int d = 0; d < 8; ++d) {
        p0[d]  = to_bf16(acc0[d] * dv);
        p1[d]  = to_bf16(acc0[d + 8] * dv);
        p2_[d] = to_bf16(acc1[d] * dv);
        p3_[d] = to_bf16(acc1[d + 8] * dv);
    }
    unsigned short* o = &xwb[n * 160 + t0 * 16];
    *(u16x8*)(o)      = p0;
    *(u16x8*)(o + 8)  = p1;
    *(u16x8*)(o + 16) = p2_;
    *(u16x8*)(o + 24) = p3_;
}

// ---- GCN gather (bf16 in, fp32 accum, bf16 out) ---------------------------
template <int W8>
__global__ __launch_bounds__(256) void k_gather_bf(
    const unsigned short* __restrict__ xs, const unsigned short* __restrict__ bucket,
    const int* __restrict__ cnt, const float* __restrict__ bias,
    unsigned short* __restrict__ hb, int total)
{
    constexpr int W = W8 * 8;
    int idx = blockIdx.x * 256 + threadIdx.x;
    if (idx >= total) return;
    int c = idx / W8, ch = idx - c * W8;
    const int deg = min(cnt[c], CAP);
    const size_t choff = (size_t)ch * 8;

    float acc[8];
#pragma unroll
    for (int i = 0; i < 8; ++i) acc[i] = 0.f;

    for (int j = 0; j < deg; j += 4) {
        ushort4 id4 = *(const ushort4*)&bucket[(size_t)c * CAP + j];
        {
            u16x8 v = *(const u16x8*)&xs[(size_t)id4.x * W + choff];
#pragma unroll
            for (int i = 0; i < 8; ++i) acc[i] += from_bf16(v[i]);
        }
        if (j + 1 < deg) {
            u16x8 v = *(const u16x8*)&xs[(size_t)id4.y * W + choff];
#pragma unroll
            for (int i = 0; i < 8; ++i) acc[i] += from_bf16(v[i]);
        }
        if (j + 2 < deg) {
            u16x8 v = *(const u16x8*)&xs[(size_t)id4.z * W + choff];
#pragma unroll
            for (int i = 0; i < 8; ++i) acc[i] += from_bf16(v[i]);
        }
        if (j + 3 < deg) {
            u16x8 v = *(const u16x8*)&xs[(size_t)id4.w * W + choff];
#pragma unroll
            for (int i = 0; i < 8; ++i) acc[i] += from_bf16(v[i]);
        }
    }

    const float dv = rsqrtf((float)cnt[c] + 1.0f);
    u16x8 sv = *(const u16x8*)&xs[(size_t)c * W + choff];
    const float* bp = &bias[(ch & 1) * 8];
    float4 b0 = *(const float4*)(bp);
    float4 b1 = *(const float4*)(bp + 4);
    float bb[8] = {b0.x, b0.y, b0.z, b0.w, b1.x, b1.y, b1.z, b1.w};
    u16x8 o;
#pragma unroll
    for (int i = 0; i < 8; ++i)
        o[i] = to_bf16(fmaxf(dv * (acc[i] + from_bf16(sv[i])) + bb[i], 0.f));
    *(u16x8*)&hb[(size_t)c * W + choff] = o;
}

// ---------------------------------------------------------------------------
// conv23 v19: gather-1 fused into stage; all-bf16 MFMA (132/wave); T-split
// weight-stationary, 16 nodes/block, 4 waves, LDS 23 KB.
// ---------------------------------------------------------------------------
__global__ __launch_bounds__(256) void k_conv23_v19(
    const unsigned short* __restrict__ xw1b, const unsigned short* __restrict__ bucket,
    const int* __restrict__ cnt, const float* __restrict__ bias1,
    const unsigned short* __restrict__ A2h, const float* __restrict__ b1b,
    const unsigned short* __restrict__ A3h, const float* __restrict__ b2a,
    const unsigned short* __restrict__ APh,
    unsigned short* __restrict__ xw2b)
{
    __shared__ unsigned short H[11520];   // H2 [16][288] then H3 [16][720] (union)

    const int tid  = threadIdx.x;
    const int wid  = tid >> 6;
    const int lane = tid & 63;
    const int base = blockIdx.x * 16;

    unsigned short* H2 = H;
    unsigned short* H3 = H;

    const int nn   = lane & 15;
    const int nb   = nn >> 3;
    const int tt   = nn & 7;
    const int g    = lane >> 4;
    const int rowb = g * 4;

    // ---- FUSED gather-1: 320 units of (node, chunk) -> relu(GCN) -> H2 ----
    for (int i = tid; i < 320; i += 256) {
        int ns = i / 20, rem = i - ns * 20;
        int c = base + ns;
        const int deg = min(cnt[c], CAP);
        const size_t choff = (size_t)rem * 8;

        float acc[8];
#pragma unroll
        for (int q = 0; q < 8; ++q) acc[q] = 0.f;

        for (int j = 0; j < deg; j += 4) {
            ushort4 id4 = *(const ushort4*)&bucket[(size_t)c * CAP + j];
            {
                u16x8 v = *(const u16x8*)&xw1b[(size_t)id4.x * 160 + choff];
#pragma unroll
                for (int q = 0; q < 8; ++q) acc[q] += from_bf16(v[q]);
            }
            if (j + 1 < deg) {
                u16x8 v = *(const u16x8*)&xw1b[(size_t)id4.y * 160 + choff];
#pragma unroll
                for (int q = 0; q < 8; ++q) acc[q] += from_bf16(v[q]);
            }
            if (j + 2 < deg) {
                u16x8 v = *(const u16x8*)&xw1b[(size_t)id4.z * 160 + choff];
#pragma unroll
                for (int q = 0; q < 8; ++q) acc[q] += from_bf16(v[q]);
            }
            if (j + 3 < deg) {
                u16x8 v = *(const u16x8*)&xw1b[(size_t)id4.w * 160 + choff];
#pragma unroll
                for (int q = 0; q < 8; ++q) acc[q] += from_bf16(v[q]);
            }
        }

        const float dv = rsqrtf((float)cnt[c] + 1.0f);
        u16x8 sv = *(const u16x8*)&xw1b[(size_t)c * 160 + choff];
        const float* bp = &bias1[(rem & 1) * 8];
        float4 b0 = *(const float4*)(bp);
        float4 b1 = *(const float4*)(bp + 4);
        float bb[8] = {b0.x, b0.y, b0.z, b0.w, b1.x, b1.y, b1.z, b1.w};
        u16x8 o;
#pragma unroll
        for (int q = 0; q < 8; ++q)
            o[q] = to_bf16(fmaxf(dv * (acc[q] + from_bf16(sv[q])) + bb[q], 0.f));

        int t = rem >> 1, ci0 = (rem & 1) * 8;
        *(u16x8*)&H2[ns * 288 + t * 24 + ci0] = o;
    }
    // zero pad rows t=10,11
    if (tid < 64) {
        int ns = tid >> 2, rem = tid & 3;
        int rrow = 10 + (rem >> 1), ci0 = (rem & 1) * 8;
        u16x8 z8 = (u16x8){0,0,0,0,0,0,0,0};
        *(u16x8*)&H2[ns * 288 + rrow * 24 + ci0] = z8;
    }
    __syncthreads();

    // ---- conv2: wave computes T=wid (a) and T=wid+4 (g) ----
    f32x4 a2[8][2];
    {
        float4 b0 = *(const float4*)&b1b[wid * 16 + rowb];
        float4 b1 = *(const float4*)&b1b[(wid + 4) * 16 + rowb];
#pragma unroll
        for (int b = 0; b < 8; ++b) {
            a2[b][0] = (f32x4){b0.x, b0.y, b0.z, b0.w};
            a2[b][1] = (f32x4){b1.x, b1.y, b1.z, b1.w};
        }
    }

#pragma unroll
    for (int s = 0; s < 2; ++s) {
        const int cib = 8 * (g & 1);
        const int kk  = 2 * s + (g >> 1);
        bf16x8 ah0 = *(const bf16x8*)&A2h[((wid * 2 + s) * 64 + lane) * 8];
        bf16x8 ah1 = *(const bf16x8*)&A2h[(((wid + 4) * 2 + s) * 64 + lane) * 8];
#pragma unroll
        for (int b = 0; b < 8; ++b) {
            const int o = (2 * b + nb) * 288 + (tt + kk) * 24 + cib;
            bf16x8 bh = *(const bf16x8*)&H2[o];
            a2[b][0] = __builtin_amdgcn_mfma_f32_16x16x32_bf16(ah0, bh, a2[b][0], 0, 0, 0);
            a2[b][1] = __builtin_amdgcn_mfma_f32_16x16x32_bf16(ah1, bh, a2[b][1], 0, 0, 0);
        }
    }
    __syncthreads();

    // ---- GLU1 -> H3 bf16 [node][t pad10][co64 stride72] ----
    {
#pragma unroll
        for (int b = 0; b < 8; ++b) {
            const int wb = (2 * b + nb) * 720 + tt * 72 + wid * 16 + rowb;
            float v0 = a2[b][0][0] * sigf(a2[b][1][0]);
            float v1 = a2[b][0][1] * sigf(a2[b][1][1]);
            float v2 = a2[b][0][2] * sigf(a2[b][1][2]);
            float v3 = a2[b][0][3] * sigf(a2[b][1][3]);
            *(ushort4*)&H3[wb] = make_ushort4(to_bf16(v0), to_bf16(v1),
                                              to_bf16(v2), to_bf16(v3));
        }
        for (int z = tid; z < 512; z += 256) {
            int ns = z / 32, rem = z % 32;
            int rrow = 8 + rem / 16, c4 = (rem % 16) * 4;
            *(ushort4*)&H3[ns * 720 + rrow * 72 + c4] = make_ushort4(0, 0, 0, 0);
        }
    }
    __syncthreads();

    // ---- conv3: K=192, 6 K-steps ----
    f32x4 a3[8][2];
    {
        float4 b0 = *(const float4*)&b2a[wid * 16 + rowb];
        float4 b1 = *(const float4*)&b2a[(wid + 4) * 16 + rowb];
#pragma unroll
        for (int b = 0; b < 8; ++b) {
            a3[b][0] = (f32x4){b0.x, b0.y, b0.z, b0.w};
            a3[b][1] = (f32x4){b1.x, b1.y, b1.z, b1.w};
        }
    }

#pragma unroll
    for (int s = 0; s < 6; ++s) {
        const int kbase = s * 32 + 8 * g;
        const int cib = kbase & 63;
        const int kk  = kbase >> 6;
        bf16x8 ah0 = *(const bf16x8*)&A3h[((wid * 6 + s) * 64 + lane) * 8];
        bf16x8 ah1 = *(const bf16x8*)&A3h[(((wid + 4) * 6 + s) * 64 + lane) * 8];
#pragma unroll
        for (int b = 0; b < 8; ++b) {
            const int o = (2 * b + nb) * 720 + (tt + kk) * 72 + cib;
            bf16x8 bh = *(const bf16x8*)&H3[o];
            a3[b][0] = __builtin_amdgcn_mfma_f32_16x16x32_bf16(ah0, bh, a3[b][0], 0, 0, 0);
            a3[b][1] = __builtin_amdgcn_mfma_f32_16x16x32_bf16(ah1, bh, a3[b][1], 0, 0, 0);
        }
    }
    __syncthreads();

    // ---- GLU2 -> h4 bf16 (overwrites H3 rows; t=6,7 garbage-but-finite) ----
    {
#pragma unroll
        for (int b = 0; b < 8; ++b) {
            const int wb = (2 * b + nb) * 720 + tt * 72 + wid * 16 + rowb;
            float v0 = a3[b][0][0] * sigf(a3[b][1][0]);
            float v1 = a3[b][0][1] * sigf(a3[b][1][1]);
            float v2 = a3[b][0][2] * sigf(a3[b][1][2]);
            float v3 = a3[b][0][3] * sigf(a3[b][1][3]);
            *(ushort4*)&H3[wb] = make_ushort4(to_bf16(v0), to_bf16(v1),
                                              to_bf16(v2), to_bf16(v3));
        }
    }
    __syncthreads();

    // ---- proj 64->16 ----
    f32x4 ap0 = (f32x4){0.f, 0.f, 0.f, 0.f};
    f32x4 ap1 = (f32x4){0.f, 0.f, 0.f, 0.f};
#pragma unroll
    for (int s = 0; s < 2; ++s) {
        const int cob = s * 32 + 8 * g;
        bf16x8 ah = *(const bf16x8*)&APh[(s * 64 + lane) * 8];
        {
            const int b = 2 * wid;
            const int o = (2 * b + nb) * 720 + tt * 72 + cob;
            bf16x8 bh = *(const bf16x8*)&H3[o];
            ap0 = __builtin_amdgcn_mfma_f32_16x16x32_bf16(ah, bh, ap0, 0, 0, 0);
        }
        {
            const int b = 2 * wid + 1;
            const int o = (2 * b + nb) * 720 + tt * 72 + cob;
            bf16x8 bh = *(const bf16x8*)&H3[o];
            ap1 = __builtin_amdgcn_mfma_f32_16x16x32_bf16(ah, bh, ap1, 0, 0, 0);
        }
    }

    if (tt < 6) {
        {
            const int ng = base + 2 * (2 * wid) + nb;
            const float dv = rsqrtf((float)cnt[ng] + 1.0f);
            ushort4 o = make_ushort4(to_bf16(ap0[0] * dv), to_bf16(ap0[1] * dv),
                                     to_bf16(ap0[2] * dv), to_bf16(ap0[3] * dv));
            *(ushort4*)&xw2b[(size_t)ng * 96 + tt * 16 + rowb] = o;
        }
        {
            const int ng = base + 2 * (2 * wid + 1) + nb;
            const float dv = rsqrtf((float)cnt[ng] + 1.0f);
            ushort4 o = make_ushort4(to_bf16(ap1[0] * dv), to_bf16(ap1[1] * dv),
                                     to_bf16(ap1[2] * dv), to_bf16(ap1[3] * dv));
            *(ushort4*)&xw2b[(size_t)ng * 96 + tt * 16 + rowb] = o;
        }
    }
}

// ---- mean-pool numerator (bf16 input) -------------------------------------
__global__ __launch_bounds__(128) void k_pool(
    const unsigned short* __restrict__ h5b, const int* __restrict__ batch,
    float* __restrict__ pool, int nNodes)
{
    int j = threadIdx.x;
    if (j >= 96) return;
    int n0 = blockIdx.x * 64;
    int n1 = min(n0 + 64, nNodes);
    int cur = batch[n0];
    float acc = 0.f;
    for (int n = n0; n < n1; ++n) {
        int g = batch[n];
        if (g != cur) { atomicAdd(&pool[cur * 96 + j], acc); acc = 0.f; cur = g; }
        acc += from_bf16(h5b[(size_t)n * 96 + j]);
    }
    atomicAdd(&pool[cur * 96 + j], acc);
}

// ---- final conv_glu (counts via binary search) ----------------------------
__global__ __launch_bounds__(256) void k_final(
    const float* __restrict__ pool, const int* __restrict__ batch,
    const float* __restrict__ w, const float* __restrict__ b,
    float* __restrict__ out, int nNodes)
{
    __shared__ float m[96];
    __shared__ float ws[6144];
    __shared__ float bs[128];
    int g = blockIdx.x, tid = threadIdx.x;

    int lo = 0, hi = nNodes;
    while (lo < hi) { int mid = (lo + hi) >> 1; if (batch[mid] < g) lo = mid + 1; else hi = mid; }
    int lo2 = lo, hi2 = nNodes;
    while (lo2 < hi2) { int mid = (lo2 + hi2) >> 1; if (batch[mid] < g + 1) lo2 = mid + 1; else hi2 = mid; }
    float cntg = fmaxf((float)(lo2 - lo), 1.0f);

    if (tid < 96) m[tid] = pool[g * 96 + tid] / cntg;
    for (int i = tid; i < 6144; i += 256) ws[i] = w[i];
    if (tid < 128) bs[tid] = b[tid];
    __syncthreads();

    int c = tid >> 2, t = tid & 3;
    float a = bs[c], gg = bs[c + 64];
#pragma unroll
    for (int ci = 0; ci < 16; ++ci)
#pragma unroll
        for (int k = 0; k < 3; ++k) {
            float xv = m[(t + k) * 16 + ci];
            a  = fmaf(ws[c * 48 + ci * 3 + k],        xv, a);
            gg = fmaf(ws[(c + 64) * 48 + ci * 3 + k], xv, gg);
        }
    out[g * 256 + c * 4 + t] = a * sigf(gg);
}

// ---------------------------------------------------------------------------
extern "C" void kernel_launch(void* const* d_in, const int* in_sizes, int n_in,
                              void* d_out, int out_size, void* d_ws, size_t ws_size,
                              hipStream_t stream)
{
    const float* x      = (const float*)d_in[0];
    const int*   ei     = (const int*)  d_in[1];
    const int*   batch  = (const int*)  d_in[2];
    const float* w_t1a  = (const float*)d_in[3];
    const float* b_t1a  = (const float*)d_in[4];
    const float* w_s1   = (const float*)d_in[5];
    const float* bb_s1  = (const float*)d_in[6];
    const float* w_t1b  = (const float*)d_in[7];
    const float* b_t1b  = (const float*)d_in[8];
    const float* w_t2a  = (const float*)d_in[9];
    const float* b_t2a  = (const float*)d_in[10];
    const float* w_s2   = (const float*)d_in[11];
    const float* bb_s2  = (const float*)d_in[12];
    const float* w_t2b  = (const float*)d_in[13];
    const float* b_t2b  = (const float*)d_in[14];
    float* out = (float*)d_out;

    const int* row = ei;
    const int* col = ei + NE;

    // workspace layout (~45 MB)
    unsigned short* U   = (unsigned short*)d_ws;
    unsigned short* xwb = U;                          // NN*160 bf16 (xw1; later h5)
    unsigned short* hb  = xwb + (size_t)NN * 160;     // NN*160 bf16 (xw2 output)
    unsigned short* A2h = hb + (size_t)NN * 160;      // 8192
    unsigned short* A3h = A2h + 8192;                 // 24576
    unsigned short* APh = A3h + 24576;                // 1024
    float* pool = (float*)(APh + 1024);               // NG*96
    int*   cnt  = (int*)(pool + NG * 96);             // NN ints
    unsigned short* bucket = (unsigned short*)(cnt + NN); // NN*CAP

    hipMemsetAsync(pool, 0, (size_t)(NG * 96 + NN) * sizeof(float), stream);

    k_fill<<<(NE + 255) / 256, 256, 0, stream>>>(row, col, cnt, bucket, NE);
    k_prep2<<<12, 256, 0, stream>>>(w_t1b, w_t2a, w_s2, A2h, A3h, APh);

    // conv_glu1 + proj -> bf16 xw1 (xwb)
    k_conv1_proj2<<<(NN * 5 + 255) / 256, 256, 0, stream>>>(
        x, w_t1a, b_t1a, w_s1, cnt, xwb, NN);

    // GCN-1 (fused) + conv2 + conv3 + proj -> bf16 xw2 (hb)
    k_conv23_v19<<<NN / 16, 256, 0, stream>>>(
        xwb, bucket, cnt, bb_s1, A2h, b_t1b, A3h, b_t2a, APh, hb);

    // GCN-2: hb -> xwb (h5)
    k_gather_bf<12><<<(NN * 12 + 255) / 256, 256, 0, stream>>>(
        hb, bucket, cnt, bb_s2, xwb, NN * 12);

    // pooling + final conv_glu
    k_pool<<<(NN + 63) / 64, 128, 0, stream>>>(xwb, batch, pool, NN);
    k_final<<<NG, 256, 0, stream>>>(pool, batch, w_t2b, b_t2b, out, NN);
}

// Round 23
// 219.166 us; speedup vs baseline: 1.1081x; 1.1081x over previous
//
#include <hip/hip_runtime.h>
#include <hip/hip_bf16.h>

// ---------------------------------------------------------------------------
// STGCN fused pipeline, round 23 = EXACT REVERT to round 21 (best: 219.2us).
// Round-22's gather-fusion experiment regressed (FETCH 8.4->82.5 MB: fusing
// the cache-friendly gather into conv23 destroyed its temporal L3 locality).
// Pipeline: fill -> prep2 -> conv1+proj(bf16) -> gather160(bf16) ->
//           conv23(MFMA, all-bf16, T-split) -> gather96(bf16) -> pool -> final.
// absmax 4.88e-4 (threshold 1.57e-3).
// ---------------------------------------------------------------------------

#define NN 50000
#define NE 500000
#define NG 16
#define CAP 64

typedef __attribute__((ext_vector_type(8))) short bf16x8;
typedef __attribute__((ext_vector_type(8))) unsigned short u16x8;
typedef __attribute__((ext_vector_type(4))) float f32x4;

__device__ __forceinline__ float sigf(float g) {
    return 1.0f / (1.0f + __expf(-g));
}

__device__ __forceinline__ unsigned short to_bf16(float f) {
    __bf16 b = (__bf16)f;                       // RNE, native cvt
    return __builtin_bit_cast(unsigned short, b);
}

__device__ __forceinline__ float from_bf16(unsigned short u) {
    return __uint_as_float(((unsigned)u) << 16);
}

// ---- bucket build ---------------------------------------------------------
__global__ void k_fill(const int* __restrict__ row, const int* __restrict__ col,
                       int* __restrict__ cnt, unsigned short* __restrict__ bucket,
                       int E)
{
    int e = blockIdx.x * 256 + threadIdx.x;
    if (e >= E) return;
    int c = col[e];
    int pos = atomicAdd(&cnt[c], 1);
    if (pos < CAP) bucket[(size_t)c * CAP + pos] = (unsigned short)row[e];
}

// ---- weight pack (bf16 RNE) into MFMA A-fragment order --------------------
__global__ void k_prep2(const float* __restrict__ w1b, const float* __restrict__ w2a,
                        const float* __restrict__ ws2,
                        unsigned short* __restrict__ A2h,
                        unsigned short* __restrict__ A3h,
                        unsigned short* __restrict__ APh)
{
    int idx = blockIdx.x * 256 + threadIdx.x;
    if (idx < 1024) {           // conv2: (T,s,lane)
        int lane = idx & 63; int r = idx >> 6; int s = r & 1; int T = r >> 1;
        int m = T * 16 + (lane & 15); int g = lane >> 4;
        for (int i = 0; i < 8; ++i) {
            int k = s * 32 + 8 * g + i;
            float w = 0.f;
            if (k < 48) { int ci = k & 15, kk = k >> 4; w = w1b[m * 48 + ci * 3 + kk]; }
            A2h[idx * 8 + i] = to_bf16(w);
        }
    }
    if (idx < 3072) {           // conv3: (T,s,lane)
        int lane = idx & 63; int r = idx >> 6; int s = r % 6; int T = r / 6;
        int m = T * 16 + (lane & 15); int g = lane >> 4;
        for (int i = 0; i < 8; ++i) {
            int k = s * 32 + 8 * g + i;
            int ci = k & 63, kk = k >> 6;
            A3h[idx * 8 + i] = to_bf16(w2a[m * 192 + ci * 3 + kk]);
        }
    }
    if (idx < 128) {            // proj: (s,lane)
        int lane = idx & 63; int s = idx >> 6;
        int d = lane & 15; int g = lane >> 4;
        for (int i = 0; i < 8; ++i) {
            int co = s * 32 + 8 * g + i;
            APh[idx * 8 + i] = to_bf16(ws2[co * 16 + d]);
        }
    }
}

// ---- conv_glu1 + proj: 2 t-outputs/thread, bf16 output --------------------
__global__ __launch_bounds__(256) void k_conv1_proj2(
    const float* __restrict__ x, const float* __restrict__ w,
    const float* __restrict__ b, const float* __restrict__ W1,
    const int* __restrict__ cnt, unsigned short* __restrict__ xwb, int nNodes)
{
    __shared__ float pk[64 * 28];
    __shared__ float bs[128];
    int tid = threadIdx.x;
    for (int i = tid; i < 1792; i += 256) {
        int c = i / 28, q = i - c * 28;
        float v;
        if (q < 6)       v = w[c * 6 + q];
        else if (q < 12) v = w[(c + 64) * 6 + (q - 6)];
        else             v = W1[c * 16 + (q - 12)];
        pk[i] = v;
    }
    if (tid < 128) bs[tid] = b[tid];
    __syncthreads();

    int idx = blockIdx.x * 256 + tid;
    if (idx >= nNodes * 5) return;
    int n = idx / 5, p = idx - n * 5;
    int t0 = 2 * p;

    float xq[2][4];
#pragma unroll
    for (int ci = 0; ci < 2; ++ci) {
        const float* xp = &x[n * 24 + ci * 12 + t0];
        float2 u0 = *(const float2*)(xp);
        float2 u1 = *(const float2*)(xp + 2);
        xq[ci][0] = u0.x; xq[ci][1] = u0.y; xq[ci][2] = u1.x; xq[ci][3] = u1.y;
    }

    float acc0[16], acc1[16];
#pragma unroll
    for (int d = 0; d < 16; ++d) { acc0[d] = 0.f; acc1[d] = 0.f; }

    for (int c = 0; c < 64; ++c) {
        const float* P = &pk[c * 28];
        float4 A = *(const float4*)(P);
        float4 B = *(const float4*)(P + 4);
        float4 C = *(const float4*)(P + 8);
        float bc = bs[c], bg = bs[c + 64];

        float a0 = bc, g0 = bg;
        a0 = fmaf(A.x, xq[0][0], a0); a0 = fmaf(A.y, xq[0][1], a0); a0 = fmaf(A.z, xq[0][2], a0);
        a0 = fmaf(A.w, xq[1][0], a0); a0 = fmaf(B.x, xq[1][1], a0); a0 = fmaf(B.y, xq[1][2], a0);
        g0 = fmaf(B.z, xq[0][0], g0); g0 = fmaf(B.w, xq[0][1], g0); g0 = fmaf(C.x, xq[0][2], g0);
        g0 = fmaf(C.y, xq[1][0], g0); g0 = fmaf(C.z, xq[1][1], g0); g0 = fmaf(C.w, xq[1][2], g0);
        float h0 = a0 * sigf(g0);

        float a1 = bc, g1 = bg;
        a1 = fmaf(A.x, xq[0][1], a1); a1 = fmaf(A.y, xq[0][2], a1); a1 = fmaf(A.z, xq[0][3], a1);
        a1 = fmaf(A.w, xq[1][1], a1); a1 = fmaf(B.x, xq[1][2], a1); a1 = fmaf(B.y, xq[1][3], a1);
        g1 = fmaf(B.z, xq[0][1], g1); g1 = fmaf(B.w, xq[0][2], g1); g1 = fmaf(C.x, xq[0][3], g1);
        g1 = fmaf(C.y, xq[1][1], g1); g1 = fmaf(C.z, xq[1][2], g1); g1 = fmaf(C.w, xq[1][3], g1);
        float h1 = a1 * sigf(g1);

        float4 D = *(const float4*)(P + 12);
        float4 E = *(const float4*)(P + 16);
        float4 F = *(const float4*)(P + 20);
        float4 G = *(const float4*)(P + 24);
        float wr[16] = {D.x, D.y, D.z, D.w, E.x, E.y, E.z, E.w,
                        F.x, F.y, F.z, F.w, G.x, G.y, G.z, G.w};
#pragma unroll
        for (int d = 0; d < 16; ++d) {
            acc0[d] = fmaf(wr[d], h0, acc0[d]);
            acc1[d] = fmaf(wr[d], h1, acc1[d]);
        }
    }
    float dv = rsqrtf((float)cnt[n] + 1.0f);
    u16x8 p0, p1, p2_, p3_;
#pragma unroll
    for (int d = 0; d < 8; ++d) {
        p0[d]  = to_bf16(acc0[d] * dv);
        p1[d]  = to_bf16(acc0[d + 8] * dv);
        p2_[d] = to_bf16(acc1[d] * dv);
        p3_[d] = to_bf16(acc1[d + 8] * dv);
    }
    unsigned short* o = &xwb[n * 160 + t0 * 16];
    *(u16x8*)(o)      = p0;
    *(u16x8*)(o + 8)  = p1;
    *(u16x8*)(o + 16) = p2_;
    *(u16x8*)(o + 24) = p3_;
}

// ---- GCN gather (bf16 in, fp32 accum, bf16 out) ---------------------------
template <int W8>   // 20 (W=160) or 12 (W=96)
__global__ __launch_bounds__(256) void k_gather_bf(
    const unsigned short* __restrict__ xs, const unsigned short* __restrict__ bucket,
    const int* __restrict__ cnt, const float* __restrict__ bias,
    unsigned short* __restrict__ hb, int total)
{
    constexpr int W = W8 * 8;
    int idx = blockIdx.x * 256 + threadIdx.x;
    if (idx >= total) return;
    int c = idx / W8, ch = idx - c * W8;
    const int deg = min(cnt[c], CAP);
    const size_t choff = (size_t)ch * 8;

    float acc[8];
#pragma unroll
    for (int i = 0; i < 8; ++i) acc[i] = 0.f;

    for (int j = 0; j < deg; j += 4) {
        ushort4 id4 = *(const ushort4*)&bucket[(size_t)c * CAP + j];
        {
            u16x8 v = *(const u16x8*)&xs[(size_t)id4.x * W + choff];
#pragma unroll
            for (int i = 0; i < 8; ++i) acc[i] += from_bf16(v[i]);
        }
        if (j + 1 < deg) {
            u16x8 v = *(const u16x8*)&xs[(size_t)id4.y * W + choff];
#pragma unroll
            for (int i = 0; i < 8; ++i) acc[i] += from_bf16(v[i]);
        }
        if (j + 2 < deg) {
            u16x8 v = *(const u16x8*)&xs[(size_t)id4.z * W + choff];
#pragma unroll
            for (int i = 0; i < 8; ++i) acc[i] += from_bf16(v[i]);
        }
        if (j + 3 < deg) {
            u16x8 v = *(const u16x8*)&xs[(size_t)id4.w * W + choff];
#pragma unroll
            for (int i = 0; i < 8; ++i) acc[i] += from_bf16(v[i]);
        }
    }

    const float dv = rsqrtf((float)cnt[c] + 1.0f);
    u16x8 sv = *(const u16x8*)&xs[(size_t)c * W + choff];
    const float* bp = &bias[(ch & 1) * 8];
    float4 b0 = *(const float4*)(bp);
    float4 b1 = *(const float4*)(bp + 4);
    float bb[8] = {b0.x, b0.y, b0.z, b0.w, b1.x, b1.y, b1.z, b1.w};
    u16x8 o;
#pragma unroll
    for (int i = 0; i < 8; ++i)
        o[i] = to_bf16(fmaxf(dv * (acc[i] + from_bf16(sv[i])) + bb[i], 0.f));
    *(u16x8*)&hb[(size_t)c * W + choff] = o;
}

// ---------------------------------------------------------------------------
// conv23 v18: all-bf16 operands, 1 MFMA per step (132/wave). T-split
// weight-stationary, 16 nodes/block, 4 waves, LDS 23 KB.
// ---------------------------------------------------------------------------
__global__ __launch_bounds__(256) void k_conv23_v18(
    const unsigned short* __restrict__ h2b,
    const unsigned short* __restrict__ A2h, const float* __restrict__ b1b,
    const unsigned short* __restrict__ A3h, const float* __restrict__ b2a,
    const unsigned short* __restrict__ APh, const int* __restrict__ cnt,
    unsigned short* __restrict__ xw2b)
{
    __shared__ unsigned short H[11520];   // H2 [16][288] then H3 [16][720] (union)

    const int tid  = threadIdx.x;
    const int wid  = tid >> 6;
    const int lane = tid & 63;
    const int base = blockIdx.x * 16;

    unsigned short* H2 = H;
    unsigned short* H3 = H;

    const int nn   = lane & 15;
    const int nb   = nn >> 3;
    const int tt   = nn & 7;
    const int g    = lane >> 4;
    const int rowb = g * 4;

    // ---- stage 16 nodes x 160 bf16 (pure copy) -> H2 [node][t pad12][ci16] ----
    for (int i = tid; i < 320; i += 256) {
        int ns = i / 20, rem = i - ns * 20;
        int t = rem >> 1, ci0 = (rem & 1) * 8;
        u16x8 v = *(const u16x8*)&h2b[(size_t)(base + ns) * 160 + t * 16 + ci0];
        *(u16x8*)&H2[ns * 288 + t * 24 + ci0] = v;
    }
    // zero pad rows t=10,11: 16 nodes x 2 rows x 2 u16x8 chunks = 64
    if (tid < 64) {
        int ns = tid >> 2, rem = tid & 3;
        int rrow = 10 + (rem >> 1), ci0 = (rem & 1) * 8;
        u16x8 z8 = (u16x8){0,0,0,0,0,0,0,0};
        *(u16x8*)&H2[ns * 288 + rrow * 24 + ci0] = z8;
    }
    __syncthreads();

    // ---- conv2: wave computes T=wid (a) and T=wid+4 (g) ----
    f32x4 a2[8][2];
    {
        float4 b0 = *(const float4*)&b1b[wid * 16 + rowb];
        float4 b1 = *(const float4*)&b1b[(wid + 4) * 16 + rowb];
#pragma unroll
        for (int b = 0; b < 8; ++b) {
            a2[b][0] = (f32x4){b0.x, b0.y, b0.z, b0.w};
            a2[b][1] = (f32x4){b1.x, b1.y, b1.z, b1.w};
        }
    }

#pragma unroll
    for (int s = 0; s < 2; ++s) {
        const int cib = 8 * (g & 1);
        const int kk  = 2 * s + (g >> 1);
        bf16x8 ah0 = *(const bf16x8*)&A2h[((wid * 2 + s) * 64 + lane) * 8];
        bf16x8 ah1 = *(const bf16x8*)&A2h[(((wid + 4) * 2 + s) * 64 + lane) * 8];
#pragma unroll
        for (int b = 0; b < 8; ++b) {
            const int o = (2 * b + nb) * 288 + (tt + kk) * 24 + cib;
            bf16x8 bh = *(const bf16x8*)&H2[o];
            a2[b][0] = __builtin_amdgcn_mfma_f32_16x16x32_bf16(ah0, bh, a2[b][0], 0, 0, 0);
            a2[b][1] = __builtin_amdgcn_mfma_f32_16x16x32_bf16(ah1, bh, a2[b][1], 0, 0, 0);
        }
    }
    __syncthreads();

    // ---- GLU1 -> H3 bf16 [node][t pad10][co64 stride72] ----
    {
#pragma unroll
        for (int b = 0; b < 8; ++b) {
            const int wb = (2 * b + nb) * 720 + tt * 72 + wid * 16 + rowb;
            float v0 = a2[b][0][0] * sigf(a2[b][1][0]);
            float v1 = a2[b][0][1] * sigf(a2[b][1][1]);
            float v2 = a2[b][0][2] * sigf(a2[b][1][2]);
            float v3 = a2[b][0][3] * sigf(a2[b][1][3]);
            *(ushort4*)&H3[wb] = make_ushort4(to_bf16(v0), to_bf16(v1),
                                              to_bf16(v2), to_bf16(v3));
        }
        for (int z = tid; z < 512; z += 256) {
            int ns = z / 32, rem = z % 32;
            int rrow = 8 + rem / 16, c4 = (rem % 16) * 4;
            *(ushort4*)&H3[ns * 720 + rrow * 72 + c4] = make_ushort4(0, 0, 0, 0);
        }
    }
    __syncthreads();

    // ---- conv3: K=192, 6 K-steps ----
    f32x4 a3[8][2];
    {
        float4 b0 = *(const float4*)&b2a[wid * 16 + rowb];
        float4 b1 = *(const float4*)&b2a[(wid + 4) * 16 + rowb];
#pragma unroll
        for (int b = 0; b < 8; ++b) {
            a3[b][0] = (f32x4){b0.x, b0.y, b0.z, b0.w};
            a3[b][1] = (f32x4){b1.x, b1.y, b1.z, b1.w};
        }
    }

#pragma unroll
    for (int s = 0; s < 6; ++s) {
        const int kbase = s * 32 + 8 * g;
        const int cib = kbase & 63;
        const int kk  = kbase >> 6;
        bf16x8 ah0 = *(const bf16x8*)&A3h[((wid * 6 + s) * 64 + lane) * 8];
        bf16x8 ah1 = *(const bf16x8*)&A3h[(((wid + 4) * 6 + s) * 64 + lane) * 8];
#pragma unroll
        for (int b = 0; b < 8; ++b) {
            const int o = (2 * b + nb) * 720 + (tt + kk) * 72 + cib;
            bf16x8 bh = *(const bf16x8*)&H3[o];
            a3[b][0] = __builtin_amdgcn_mfma_f32_16x16x32_bf16(ah0, bh, a3[b][0], 0, 0, 0);
            a3[b][1] = __builtin_amdgcn_mfma_f32_16x16x32_bf16(ah1, bh, a3[b][1], 0, 0, 0);
        }
    }
    __syncthreads();

    // ---- GLU2 -> h4 bf16 (overwrites H3 rows; t=6,7 garbage-but-finite) ----
    {
#pragma unroll
        for (int b = 0; b < 8; ++b) {
            const int wb = (2 * b + nb) * 720 + tt * 72 + wid * 16 + rowb;
            float v0 = a3[b][0][0] * sigf(a3[b][1][0]);
            float v1 = a3[b][0][1] * sigf(a3[b][1][1]);
            float v2 = a3[b][0][2] * sigf(a3[b][1][2]);
            float v3 = a3[b][0][3] * sigf(a3[b][1][3]);
            *(ushort4*)&H3[wb] = make_ushort4(to_bf16(v0), to_bf16(v1),
                                              to_bf16(v2), to_bf16(v3));
        }
    }
    __syncthreads();

    // ---- proj 64->16 ----
    f32x4 ap0 = (f32x4){0.f, 0.f, 0.f, 0.f};
    f32x4 ap1 = (f32x4){0.f, 0.f, 0.f, 0.f};
#pragma unroll
    for (int s = 0; s < 2; ++s) {
        const int cob = s * 32 + 8 * g;
        bf16x8 ah = *(const bf16x8*)&APh[(s * 64 + lane) * 8];
        {
            const int b = 2 * wid;
            const int o = (2 * b + nb) * 720 + tt * 72 + cob;
            bf16x8 bh = *(const bf16x8*)&H3[o];
            ap0 = __builtin_amdgcn_mfma_f32_16x16x32_bf16(ah, bh, ap0, 0, 0, 0);
        }
        {
            const int b = 2 * wid + 1;
            const int o = (2 * b + nb) * 720 + tt * 72 + cob;
            bf16x8 bh = *(const bf16x8*)&H3[o];
            ap1 = __builtin_amdgcn_mfma_f32_16x16x32_bf16(ah, bh, ap1, 0, 0, 0);
        }
    }

    if (tt < 6) {
        {
            const int ng = base + 2 * (2 * wid) + nb;
            const float dv = rsqrtf((float)cnt[ng] + 1.0f);
            ushort4 o = make_ushort4(to_bf16(ap0[0] * dv), to_bf16(ap0[1] * dv),
                                     to_bf16(ap0[2] * dv), to_bf16(ap0[3] * dv));
            *(ushort4*)&xw2b[(size_t)ng * 96 + tt * 16 + rowb] = o;
        }
        {
            const int ng = base + 2 * (2 * wid + 1) + nb;
            const float dv = rsqrtf((float)cnt[ng] + 1.0f);
            ushort4 o = make_ushort4(to_bf16(ap1[0] * dv), to_bf16(ap1[1] * dv),
                                     to_bf16(ap1[2] * dv), to_bf16(ap1[3] * dv));
            *(ushort4*)&xw2b[(size_t)ng * 96 + tt * 16 + rowb] = o;
        }
    }
}

// ---- mean-pool numerator (bf16 input) -------------------------------------
__global__ __launch_bounds__(128) void k_pool(
    const unsigned short* __restrict__ h5b, const int* __restrict__ batch,
    float* __restrict__ pool, int nNodes)
{
    int j = threadIdx.x;
    if (j >= 96) return;
    int n0 = blockIdx.x * 64;
    int n1 = min(n0 + 64, nNodes);
    int cur = batch[n0];
    float acc = 0.f;
    for (int n = n0; n < n1; ++n) {
        int g = batch[n];
        if (g != cur) { atomicAdd(&pool[cur * 96 + j], acc); acc = 0.f; cur = g; }
        acc += from_bf16(h5b[(size_t)n * 96 + j]);
    }
    atomicAdd(&pool[cur * 96 + j], acc);
}

// ---- final conv_glu (counts via binary search) ----------------------------
__global__ __launch_bounds__(256) void k_final(
    const float* __restrict__ pool, const int* __restrict__ batch,
    const float* __restrict__ w, const float* __restrict__ b,
    float* __restrict__ out, int nNodes)
{
    __shared__ float m[96];
    __shared__ float ws[6144];
    __shared__ float bs[128];
    int g = blockIdx.x, tid = threadIdx.x;

    int lo = 0, hi = nNodes;
    while (lo < hi) { int mid = (lo + hi) >> 1; if (batch[mid] < g) lo = mid + 1; else hi = mid; }
    int lo2 = lo, hi2 = nNodes;
    while (lo2 < hi2) { int mid = (lo2 + hi2) >> 1; if (batch[mid] < g + 1) lo2 = mid + 1; else hi2 = mid; }
    float cntg = fmaxf((float)(lo2 - lo), 1.0f);

    if (tid < 96) m[tid] = pool[g * 96 + tid] / cntg;
    for (int i = tid; i < 6144; i += 256) ws[i] = w[i];
    if (tid < 128) bs[tid] = b[tid];
    __syncthreads();

    int c = tid >> 2, t = tid & 3;
    float a = bs[c], gg = bs[c + 64];
#pragma unroll
    for (int ci = 0; ci < 16; ++ci)
#pragma unroll
        for (int k = 0; k < 3; ++k) {
            float xv = m[(t + k) * 16 + ci];
            a  = fmaf(ws[c * 48 + ci * 3 + k],        xv, a);
            gg = fmaf(ws[(c + 64) * 48 + ci * 3 + k], xv, gg);
        }
    out[g * 256 + c * 4 + t] = a * sigf(gg);
}

// ---------------------------------------------------------------------------
extern "C" void kernel_launch(void* const* d_in, const int* in_sizes, int n_in,
                              void* d_out, int out_size, void* d_ws, size_t ws_size,
                              hipStream_t stream)
{
    const float* x      = (const float*)d_in[0];
    const int*   ei     = (const int*)  d_in[1];
    const int*   batch  = (const int*)  d_in[2];
    const float* w_t1a  = (const float*)d_in[3];
    const float* b_t1a  = (const float*)d_in[4];
    const float* w_s1   = (const float*)d_in[5];
    const float* bb_s1  = (const float*)d_in[6];
    const float* w_t1b  = (const float*)d_in[7];
    const float* b_t1b  = (const float*)d_in[8];
    const float* w_t2a  = (const float*)d_in[9];
    const float* b_t2a  = (const float*)d_in[10];
    const float* w_s2   = (const float*)d_in[11];
    const float* bb_s2  = (const float*)d_in[12];
    const float* w_t2b  = (const float*)d_in[13];
    const float* b_t2b  = (const float*)d_in[14];
    float* out = (float*)d_out;

    const int* row = ei;
    const int* col = ei + NE;

    // workspace layout (~45 MB)
    unsigned short* U   = (unsigned short*)d_ws;
    unsigned short* xwb = U;                          // NN*160 bf16
    unsigned short* hb  = xwb + (size_t)NN * 160;     // NN*160 bf16
    unsigned short* A2h = hb + (size_t)NN * 160;      // 8192
    unsigned short* A3h = A2h + 8192;                 // 24576
    unsigned short* APh = A3h + 24576;                // 1024
    float* pool = (float*)(APh + 1024);               // NG*96
    int*   cnt  = (int*)(pool + NG * 96);             // NN ints
    unsigned short* bucket = (unsigned short*)(cnt + NN); // NN*CAP

    hipMemsetAsync(pool, 0, (size_t)(NG * 96 + NN) * sizeof(float), stream);

    k_fill<<<(NE + 255) / 256, 256, 0, stream>>>(row, col, cnt, bucket, NE);
    k_prep2<<<12, 256, 0, stream>>>(w_t1b, w_t2a, w_s2, A2h, A3h, APh);

    k_conv1_proj2<<<(NN * 5 + 255) / 256, 256, 0, stream>>>(
        x, w_t1a, b_t1a, w_s1, cnt, xwb, NN);

    k_gather_bf<20><<<(NN * 20 + 255) / 256, 256, 0, stream>>>(
        xwb, bucket, cnt, bb_s1, hb, NN * 20);

    k_conv23_v18<<<NN / 16, 256, 0, stream>>>(
        hb, A2h, b_t1b, A3h, b_t2a, APh, cnt, xwb);

    k_gather_bf<12><<<(NN * 12 + 255) / 256, 256, 0, stream>>>(
        xwb, bucket, cnt, bb_s2, hb, NN * 12);

    k_pool<<<(NN + 63) / 64, 128, 0, stream>>>(hb, batch, pool, NN);
    k_final<<<NG, 256, 0, stream>>>(pool, batch, w_t2b, b_t2b, out, NN);
}